// Round 8
// baseline (170.415 us; speedup 1.0000x reference)
//
#include <hip/hip_runtime.h>
#include <stdint.h>

// MeshConvPoint: B=8, C=64, V=25000, D=12, O=64
// out[b,o,v] = bias[o] + sum_c W0[o,c]*x[b,c,v] + (1/deg)*sum_{d<deg} y1[b,o,nbr[b,v,d]]
//
// R8: batched staging loads in ygemm. R7 counters (45us, 23% HBM, 11% VALU,
// occupancy 22.9% ~ 1.8 blocks/CU) = per-iteration waitcnt in the staging loop
// serialized 16 HBM round-trips (~12us/block). Fix: phase A issues all 32
// independent loads into regs, phase B packs+ds_writes after one waitcnt.
// Same two-phase trick that fixed gather in R5. Everything else unchanged.
// XCD pin everywhere: blockIdx.x & 7 == batch; per-batch y1 (3.2 MB bf16)
// stays in that XCD's 4 MB L2.

#define NB 8
#define NC 64
#define NV 25000
#define ND 12
#define NO 64
#define VTILE 128
#define NGT 196        // ceil(25000/128) vertex tiles for gemm
#define GVT 782        // ceil(25000/32)  vertex tiles for gather (32 v / block)

typedef uint32_t u32x4 __attribute__((ext_vector_type(4)));
typedef uint32_t u32x2 __attribute__((ext_vector_type(2)));
typedef __bf16  bf16x8 __attribute__((ext_vector_type(8)));
typedef float   f32x4  __attribute__((ext_vector_type(4)));

__device__ inline uint32_t bf16pack(float a, float b) {
    uint32_t ua = __float_as_uint(a), ub = __float_as_uint(b);
    ua = (ua + 0x7fffu + ((ua >> 16) & 1u)) >> 16;
    ub = (ub + 0x7fffu + ((ub >> 16) & 1u)) >> 16;
    return ua | (ub << 16);
}
__device__ inline float blo(uint32_t u) { return __uint_as_float(u << 16); }
__device__ inline float bhi(uint32_t u) { return __uint_as_float(u & 0xffff0000u); }

// ---- K0: W[o][c][k] -> Wcb[m][c] bf16, m = k*64 + o ----
__global__ __launch_bounds__(256) void wt_kernel(const float* __restrict__ W,
                                                 uint32_t* __restrict__ Wcb) {
    int i = blockIdx.x * 256 + threadIdx.x;  // i in [0, 4096)
    int m = i >> 5;             // 0..127
    int c = (i & 31) * 2;       // 0..62 even
    int k = m >> 6;             // plane
    int o = m & 63;
    float s0 = W[o * (NC * 2) + c * 2 + k];
    float s1 = W[o * (NC * 2) + (c + 1) * 2 + k];
    Wcb[i] = bf16pack(s0, s1);
}

// ---- K1: MFMA GEMM with LDS-staged x tile, batched staging loads ----
__global__ __launch_bounds__(256) void ygemm_mfma(const float* __restrict__ x,
                                                  const uint32_t* __restrict__ Wcb,
                                                  const float* __restrict__ bias,
                                                  uint32_t* __restrict__ y0,
                                                  uint32_t* __restrict__ y1) {
    __shared__ uint32_t xt[VTILE * 36];  // [v][c] bf16 pairs, 144B row stride

    const int b = blockIdx.x & 7;      // XCD pin
    const int tile = blockIdx.x >> 3;
    const int vbase = tile * VTILE;
    const int tid = threadIdx.x;
    const float* xb = x + (size_t)b * NC * NV;

    // staging: thread covers v = tid&127, c-pair p = r*2 + (tid>>7), r=0..15
    {
        const int vl = tid & 127;
        const int ph = tid >> 7;       // 0..1
        int vg = vbase + vl;
        if (vg >= NV) vg = NV - 1;
        const float* base = xb + vg;
        float sA[16], sB[16];
        // phase A: issue all 32 independent loads (one waitcnt total)
#pragma unroll
        for (int r = 0; r < 16; ++r) {
            const int c = (r * 2 + ph) * 2;
            sA[r] = __builtin_nontemporal_load(base + (size_t)c * NV);
            sB[r] = __builtin_nontemporal_load(base + (size_t)(c + 1) * NV);
        }
        // phase B: pack + LDS write
#pragma unroll
        for (int r = 0; r < 16; ++r)
            xt[vl * 36 + r * 2 + ph] = bf16pack(sA[r], sB[r]);
    }
    __syncthreads();

    const int lane = tid & 63, wave = tid >> 6;
    const int l15 = lane & 15, lq = lane >> 4;

    // B frags: wave handles subtiles s=0,1 -> vloc = (wave*2+s)*16 + l15.
    // B[k][n]: n = l15 (v), k = lq*8 + j  -> 16 contiguous bytes in xt row.
    union BF { u32x4 q; bf16x8 v; } bf[2][2];  // [sub][kt]
#pragma unroll
    for (int s = 0; s < 2; ++s) {
        const int vloc = (wave * 2 + s) * 16 + l15;
#pragma unroll
        for (int kt = 0; kt < 2; ++kt)
            bf[s][kt].q = *reinterpret_cast<const u32x4*>(&xt[vloc * 36 + kt * 16 + lq * 4]);
    }

    f32x4 acc[2][8];
#pragma unroll
    for (int s = 0; s < 2; ++s)
#pragma unroll
        for (int mt = 0; mt < 8; ++mt) acc[s][mt] = (f32x4){0.f, 0.f, 0.f, 0.f};

    // A frags loaded once per (kt,mt), reused for both subtiles
#pragma unroll
    for (int kt = 0; kt < 2; ++kt) {
#pragma unroll
        for (int mt = 0; mt < 8; ++mt) {
            union { u32x4 q; bf16x8 v; } au;
            au.q = *(const u32x4*)(Wcb + (size_t)(mt * 16 + l15) * 32 + kt * 16 + lq * 4);
#pragma unroll
            for (int s = 0; s < 2; ++s)
                acc[s][mt] = __builtin_amdgcn_mfma_f32_16x16x32_bf16(au.v, bf[s][kt].v,
                                                                     acc[s][mt], 0, 0, 0);
        }
    }

    // D: lane holds D[m = mt*16 + lq*4 + r][n = v], r = 0..3 consecutive o
#pragma unroll
    for (int s = 0; s < 2; ++s) {
        const int v = vbase + (wave * 2 + s) * 16 + l15;
        if (v < NV) {
            uint32_t* yr0 = y0 + ((size_t)b * NV + v) * 32;
            uint32_t* yr1 = y1 + ((size_t)b * NV + v) * 32;
#pragma unroll
            for (int mt = 0; mt < 8; ++mt) {
                const int mo = mt * 16 + lq * 4;
                f32x4 a = acc[s][mt];
                if (mt < 4) {  // plane 0: + bias, nt store (read exactly once later)
                    const float* bp = bias + mo;
                    a[0] += bp[0]; a[1] += bp[1]; a[2] += bp[2]; a[3] += bp[3];
                    u32x2 p = {bf16pack(a[0], a[1]), bf16pack(a[2], a[3])};
                    __builtin_nontemporal_store(p, (u32x2*)(yr0 + (mo >> 1)));
                } else {       // plane 1: hot gather target, keep cached in L2
                    u32x2 p = {bf16pack(a[0], a[1]), bf16pack(a[2], a[3])};
                    *(u32x2*)(yr1 + ((mo - 64) >> 1)) = p;
                }
            }
        }
    }
}

// ---- K2: gather, 8 lanes/vertex + LDS transpose for coalesced stores ----
__global__ __launch_bounds__(256) void gather_out(const int* __restrict__ nbr,
                                                  const int* __restrict__ deg,
                                                  const uint32_t* __restrict__ y0,
                                                  const uint32_t* __restrict__ y1,
                                                  float* __restrict__ out) {
    __shared__ float lds[32 * 68];  // [vloc][o], stride 68 to spread banks

    const int b = blockIdx.x & 7;  // same XCD pin as producer
    const int tile = blockIdx.x >> 3;
    const int lane = threadIdx.x & 63;
    const int wave = threadIdx.x >> 6;
    const int s = lane >> 3;
    const int j = lane & 7;
    const int vloc = wave * 8 + s;       // 0..31
    const int v = tile * 32 + vloc;
    const int vc = v < NV ? v : NV - 1;
    const size_t bv = (size_t)b * NV + vc;

    int idxr[ND];
    {
        const int4* p = reinterpret_cast<const int4*>(nbr + bv * ND);
        int4 a0 = p[0], a1 = p[1], a2 = p[2];
        idxr[0] = a0.x; idxr[1] = a0.y; idxr[2]  = a0.z; idxr[3]  = a0.w;
        idxr[4] = a1.x; idxr[5] = a1.y; idxr[6]  = a1.z; idxr[7]  = a1.w;
        idxr[8] = a2.x; idxr[9] = a2.y; idxr[10] = a2.z; idxr[11] = a2.w;
    }
    const int dg = deg[bv];
    const float inv = 1.0f / (float)dg;
    const uint32_t* y1b = y1 + (size_t)b * NV * 32;

    // self row chunk (read once, nt): per instr 8 rows x 128B fully used
    u32x4 su = __builtin_nontemporal_load(
        reinterpret_cast<const u32x4*>(y0 + bv * 32) + j);

    // phase 1: issue all masked row-chunk loads (up to 12 outstanding)
    u32x4 rows[ND];
#pragma unroll
    for (int d = 0; d < ND; ++d) {
        if (d < dg)
            rows[d] = *(reinterpret_cast<const u32x4*>(y1b + (size_t)idxr[d] * 32) + j);
    }

    // phase 2: accumulate
    float ns[8];
#pragma unroll
    for (int t = 0; t < 8; ++t) ns[t] = 0.0f;
#pragma unroll
    for (int d = 0; d < ND; ++d) {
        if (d < dg) {
            u32x4 u = rows[d];
            ns[0] += blo(u[0]); ns[1] += bhi(u[0]);
            ns[2] += blo(u[1]); ns[3] += bhi(u[1]);
            ns[4] += blo(u[2]); ns[5] += bhi(u[2]);
            ns[6] += blo(u[3]); ns[7] += bhi(u[3]);
        }
    }

    // combine + stage to LDS (16B-aligned float4 writes; 68*4 stride)
    {
        float f[8];
        f[0] = __builtin_fmaf(inv, ns[0], blo(su[0]));
        f[1] = __builtin_fmaf(inv, ns[1], bhi(su[0]));
        f[2] = __builtin_fmaf(inv, ns[2], blo(su[1]));
        f[3] = __builtin_fmaf(inv, ns[3], bhi(su[1]));
        f[4] = __builtin_fmaf(inv, ns[4], blo(su[2]));
        f[5] = __builtin_fmaf(inv, ns[5], bhi(su[2]));
        f[6] = __builtin_fmaf(inv, ns[6], blo(su[3]));
        f[7] = __builtin_fmaf(inv, ns[7], bhi(su[3]));
        f32x4 w0 = {f[0], f[1], f[2], f[3]};
        f32x4 w1 = {f[4], f[5], f[6], f[7]};
        *reinterpret_cast<f32x4*>(&lds[vloc * 68 + j * 8])     = w0;
        *reinterpret_cast<f32x4*>(&lds[vloc * 68 + j * 8 + 4]) = w1;
    }
    __syncthreads();

    // store phase: per wave-instruction 2 o-rows x 32 consecutive v (2x128B)
    {
        const int vl = threadIdx.x & 31;
        const int o8 = threadIdx.x >> 5;   // 0..7
        const int vv = tile * 32 + vl;
        if (vv < NV) {
            float* ob = out + (size_t)b * NO * NV + vv;
#pragma unroll
            for (int oo = 0; oo < 8; ++oo) {
                const int o = oo * 8 + o8;
                __builtin_nontemporal_store(lds[vl * 68 + o], ob + (size_t)o * NV);
            }
        }
    }
}

// ---- Fallback (workspace too small): correct but slow ----
__global__ __launch_bounds__(64) void fallback_kernel(const float* __restrict__ x,
                                                      const int* __restrict__ nbr,
                                                      const int* __restrict__ deg,
                                                      const float* __restrict__ W,
                                                      const float* __restrict__ bias,
                                                      float* __restrict__ out) {
    const int bvi = blockIdx.x;
    const int b = bvi / NV, v = bvi % NV;
    const int o = threadIdx.x;
    const int degv = deg[bvi];
    const float inv = 1.0f / (float)degv;
    float acc = bias[o];
    for (int c = 0; c < NC; ++c) {
        const float* xc = x + ((size_t)b * NC + c) * NV;
        float m = 0.0f;
        for (int d = 0; d < degv; ++d) m += xc[nbr[(size_t)bvi * ND + d]];
        acc += W[o * (NC * 2) + c * 2] * xc[v] + W[o * (NC * 2) + c * 2 + 1] * (m * inv);
    }
    out[((size_t)b * NO + o) * NV + v] = acc;
}

extern "C" void kernel_launch(void* const* d_in, const int* in_sizes, int n_in,
                              void* d_out, int out_size, void* d_ws, size_t ws_size,
                              hipStream_t stream) {
    const float* x    = (const float*)d_in[0];
    const int*   nbr  = (const int*)d_in[1];
    const int*   deg  = (const int*)d_in[2];
    const float* W    = (const float*)d_in[3];
    const float* bias = (const float*)d_in[4];
    float* out = (float*)d_out;

    const size_t wcb_dw = 4096;                   // 128x64 bf16 as dwords
    const size_t yplane = (size_t)NB * NV * 32;   // dwords per plane
    const size_t need = (wcb_dw + 2 * yplane) * 4;
    if (ws_size >= need) {
        uint32_t* Wcb = (uint32_t*)d_ws;
        uint32_t* y0 = Wcb + wcb_dw;
        uint32_t* y1 = y0 + yplane;
        wt_kernel<<<dim3(16), 256, 0, stream>>>(W, Wcb);
        ygemm_mfma<<<dim3(NB * NGT), 256, 0, stream>>>(x, Wcb, bias, y0, y1);
        gather_out<<<dim3(NB * GVT), 256, 0, stream>>>(nbr, deg, y0, y1, out);
    } else {
        fallback_kernel<<<dim3(NB * NV), 64, 0, stream>>>(x, nbr, deg, W, bias, out);
    }
}